// Round 5
// baseline (533.124 us; speedup 1.0000x reference)
//
#include <hip/hip_runtime.h>
#include <hip/hip_bf16.h>
#include <math.h>

// Problem constants
#define B_TOK 4096
#define NE 16
#define DI 1024
#define DH 2048
#define DOUT 1024
#define NSLOT (B_TOK * 2)   // 8192 (token, expert) assignments, exactly

typedef unsigned short u16;
typedef short bfrag __attribute__((ext_vector_type(8)));   // 8 bf16 input frag (4 VGPRs)
typedef float f32x4 __attribute__((ext_vector_type(4)));   // MFMA accumulator
typedef u16 u16x4 __attribute__((ext_vector_type(4)));
typedef u16 u16x8 __attribute__((ext_vector_type(8)));

// ---------- helpers ----------
__device__ __forceinline__ u16 f2bf(float f) {   // fp32 -> bf16 round-to-nearest-even
    union { float f; unsigned u; } v; v.f = f;
    return (u16)((v.u + 0x7fffu + ((v.u >> 16) & 1u)) >> 16);
}

// async 16B/lane global->LDS. LDS dest must be wave-uniform base (+lane*16 by HW).
__device__ __forceinline__ void async16(const void* g, void* lds) {
    __builtin_amdgcn_global_load_lds(
        (const __attribute__((address_space(1))) void*)g,
        (__attribute__((address_space(3))) void*)lds,
        16, 0, 0);
}

// ---------- kernel 0: zero output ----------
__global__ void zero_init(float* __restrict__ out, int n4) {
    int i = blockIdx.x * blockDim.x + threadIdx.x;
    if (i < n4) ((float4*)out)[i] = make_float4(0.f, 0.f, 0.f, 0.f);
}

// ---------- kernel 1: fp32 -> bf16 convert, 8 elems/thread (weights) ----------
__global__ void convert_bf16(const float* __restrict__ src, u16* __restrict__ dst, int n8) {
    int i = blockIdx.x * blockDim.x + threadIdx.x;
    if (i >= n8) return;
    const float4* s4 = (const float4*)src;
    float4 a = s4[2 * i], b = s4[2 * i + 1];
    u16x8 r;
    r[0] = f2bf(a.x); r[1] = f2bf(a.y); r[2] = f2bf(a.z); r[3] = f2bf(a.w);
    r[4] = f2bf(b.x); r[5] = f2bf(b.y); r[6] = f2bf(b.z); r[7] = f2bf(b.w);
    ((u16x8*)dst)[i] = r;
}

// ---------- kernel 2: gating (fp64 dots for exact top-k ordering) + fused x->bf16 ----------
__global__ __launch_bounds__(256) void gate_topk(
    const float* __restrict__ x, const float* __restrict__ gw,
    int* __restrict__ token_e, float* __restrict__ token_w,
    u16* __restrict__ xb)
{
    int wave = threadIdx.x >> 6, lane = threadIdx.x & 63;
    int t = blockIdx.x * 4 + wave;            // grid 1024 * 4 waves = 4096 tokens
    const float4* x4 = (const float4*)(x + (size_t)t * DI);
    const float4* g4 = (const float4*)gw;
    u16x4* xb4 = (u16x4*)(xb + (size_t)t * DI);
    double acc[NE];
#pragma unroll
    for (int e = 0; e < NE; ++e) acc[e] = 0.0;
#pragma unroll
    for (int i = 0; i < 4; ++i) {
        float4 xv = x4[lane + i * 64];
        u16x4 xc; xc[0] = f2bf(xv.x); xc[1] = f2bf(xv.y); xc[2] = f2bf(xv.z); xc[3] = f2bf(xv.w);
        xb4[lane + i * 64] = xc;              // fused x convert (coalesced 8B/lane)
#pragma unroll
        for (int e = 0; e < NE; ++e) {
            float4 gv = g4[e * 256 + lane + i * 64];
            acc[e] += (double)xv.x * gv.x + (double)xv.y * gv.y
                    + (double)xv.z * gv.z + (double)xv.w * gv.w;
        }
    }
#pragma unroll
    for (int e = 0; e < NE; ++e) {
        double v = acc[e];
        for (int off = 32; off; off >>= 1) v += __shfl_xor(v, off, 64);
        acc[e] = v;
    }
    if (lane == 0) {
        int e0 = 0; double v0 = acc[0];
#pragma unroll
        for (int e = 1; e < NE; ++e) if (acc[e] > v0) { v0 = acc[e]; e0 = e; }
        int e1 = -1; double v1 = -1e300;
#pragma unroll
        for (int e = 0; e < NE; ++e) if (e != e0 && acc[e] > v1) { v1 = acc[e]; e1 = e; }
        float d = expf((float)(v1 - v0));        // v1 <= v0, d in (0,1]
        float w0 = 1.f / (1.f + d);
        float w1 = d * w0;
        token_e[2 * t] = e0; token_e[2 * t + 1] = e1;
        token_w[2 * t] = w0; token_w[2 * t + 1] = w1;
    }
}

// ---------- kernel 3: routing — histogram + scan + slot fill, one block, LDS atomics ----------
__global__ __launch_bounds__(1024) void route(
    const int* __restrict__ token_e, const float* __restrict__ token_w,
    int* __restrict__ counts, int* __restrict__ offsets,
    int* __restrict__ slot_token, float* __restrict__ slot_wgt)
{
    __shared__ int lcnt[NE];
    __shared__ int lcur[NE];
    int tid = threadIdx.x;
    if (tid < NE) lcnt[tid] = 0;
    __syncthreads();
    for (int i = tid; i < NSLOT; i += 1024) atomicAdd(&lcnt[token_e[i]], 1);
    __syncthreads();
    if (tid == 0) {
        int s = 0;
        for (int e = 0; e < NE; ++e) {
            int c = lcnt[e];
            counts[e] = c; offsets[e] = s; lcur[e] = s; s += c;
        }
    }
    __syncthreads();
    for (int i = tid; i < NSLOT; i += 1024) {
        int e = token_e[i];
        int pos = atomicAdd(&lcur[e], 1);
        slot_token[pos] = i >> 1;
        slot_wgt[pos] = token_w[i];
    }
}

// ---------- grouped GEMM v5: 128x128, BK=64, 4 waves, dbuf + counted-vmcnt pipeline ----------
// (Resubmission of round-4 source: bench infra failed twice; no kernel data was produced.
//  Deadlock audit: barriers are uniform-control-flow; vmcnt waits are per-wave counted over
//  exactly-8-load STAGEs with in-order retirement; all raw s_barriers are sched_barrier(0)
//  fenced on the racing side. No unsatisfiable wait exists.)
// Post-mortem r3: MfmaUtil stuck at 14%. Cycle model (corrected: mfma_16x16x32 = ~16 cy on
// its SIMD): compute phase/step = 32 MFMA ~= 512 cy, but the stage->vmcnt(0)-drain exposes
// the full L3/HBM load latency (~600-900 cy) every step (all concurrent m-blocks of a B
// panel miss together). Fix = T3+T4 minimum pipeline (m218 derived-waits):
//   [wait vmcnt(8); s_barrier; compute buf[kt&1]; s_barrier; stage(kt+2 -> buf[kt&1])]
// Two NON-draining barriers/step; per-wave counted vmcnt (each wave issues exactly 8
// global_load_lds per tile; 16 in flight steady-state; tail peels to vmcnt(0)).
// Issue-to-consume distance ~= 1.5 iterations (~800+ cy) -> latency hidden under MFMA.
// LDS 2x32KB = 64KB -> 2 blocks/CU. Swizzle unchanged from r2/r3 (measured 0 conflicts):
// rows = 8 x 16B chunks, physical chunk = logical ^ (row&7); pre-swizzled global source
// (rule #21, linear LDS dest), same XOR on ds_read.
// PHASE 1: h = relu(x_sel @ w1[e]^T + b1[e]) -> hb (bf16).        KB=1024, nk=16
// PHASE 2: out[token] += wgt*(h @ w2[e]^T + (sp==0 ? b2[e] : 0)). KB=1024 (x2 K-splits)
template <int PHASE>
__global__ __launch_bounds__(256, 2) void moe_gemm(
    const u16* __restrict__ Abuf,   // PHASE1: xb [4096][1024]; PHASE2: hb [8192][2048]
    const u16* __restrict__ Bbuf,   // bf16 weights: [NE][NDIM][KDIM_T] (K contiguous)
    const float* __restrict__ bias, // [NE][NDIM] fp32
    const int* __restrict__ counts, const int* __restrict__ offsets,
    const int* __restrict__ slot_token, const float* __restrict__ slot_wgt,
    u16* __restrict__ hb, float* __restrict__ out)
{
    constexpr int KDIM_T = (PHASE == 1) ? DI : DH;   // full K (A/B row stride)
    constexpr int KB = 1024;                         // K handled per block (both phases)
    constexpr int NS = (PHASE == 1) ? 1 : 2;         // K-splits
    constexpr int NDIM = (PHASE == 1) ? DH : DOUT;
    constexpr int BM = 128, BN = 128, BK = 64;       // row = 128B = 8 x 16B chunks
    constexpr int GA = BM / 8, GB = BN / 8;          // 16 + 16 staging groups (1KB each)
    constexpr int GPW = (GA + GB) / 4;               // 8 async16 per wave per tile
    constexpr int NT = NDIM / BN;                    // 16 / 8
    constexpr int MT = B_TOK / BM;                   // 32
    constexpr int TOTAL = NE * NS * NT * MT;         // 8192 both phases
    constexpr int PER_XCD = TOTAL / 8;               // 1024

    // XCD-chunked bijective swizzle; e-major -> split -> n-tile -> m-tile (mt-consecutive
    // blocks share a 256KB B panel in their XCD's L2; each XCD owns exactly 2 experts)
    const int id = blockIdx.x;
    const int wg = (id & 7) * PER_XCD + (id >> 3);
    const int e   = wg / (NS * NT * MT);
    int rem = wg % (NS * NT * MT);
    const int sp  = rem / (NT * MT);
    rem %= (NT * MT);
    const int nt  = rem / MT;
    const int mt  = rem % MT;

    const int cnt = counts[e];
    const int m0 = mt * BM;
    if (m0 >= cnt) return;                    // block-uniform early exit (before any barrier)
    const int n0 = nt * BN;
    const int sbase = offsets[e];
    const int koff = sp * KB;                 // element offset into K

    __shared__ u16 lds[2][(BM + BN) * BK];    // 2 x 32 KB double buffer

    const int tid = threadIdx.x;
    const int wv = tid >> 6, lane = tid & 63;
    const int quad = lane >> 4, mr = lane & 15;
    const int wr = wv >> 1, wc = wv & 1;      // 2x2 wave grid, 64x64 per wave

    // ---- staging pointers: per-lane global source, pre-swizzled (rule #21) ----
    // lane covers (r = lane>>3, s = lane&7) of an 8-row x 128B group; fetches chunk s^r
    const int sr_ = lane >> 3, sc_ = lane & 7;
    const int sw = (sc_ ^ sr_) * 8;                        // u16 offset within 128B row seg
    const u16* gptr[GPW];
#pragma unroll
    for (int j = 0; j < GPW; ++j) {
        const int G = wv * GPW + j;                        // wave-uniform group id
        if (G < GA) {                                      // A group: tile rows 8G..8G+7
            int row = G * 8 + sr_;
            if (PHASE == 1) {
                int rr = m0 + row; if (rr > cnt - 1) rr = cnt - 1;
                gptr[j] = Abuf + (size_t)slot_token[sbase + rr] * KDIM_T + koff + sw;
            } else {
                int s2 = sbase + m0 + row; if (s2 > NSLOT - 1) s2 = NSLOT - 1;
                gptr[j] = Abuf + (size_t)s2 * KDIM_T + koff + sw;
            }
        } else {                                           // B group
            int row = (G - GA) * 8 + sr_;
            gptr[j] = Bbuf + (size_t)e * NDIM * KDIM_T + (size_t)(n0 + row) * KDIM_T + koff + sw;
        }
    }

    f32x4 acc[4][4];
#pragma unroll
    for (int i = 0; i < 4; ++i)
#pragma unroll
        for (int j = 0; j < 4; ++j) acc[i][j] = (f32x4){0.f, 0.f, 0.f, 0.f};

    constexpr int nk = KB / BK;               // 16

    // stage tile kt into buffer bb (8 x async16/wave; LDS dest linear, source pre-swizzled)
    auto STAGE = [&](int kt, int bb) {
#pragma unroll
        for (int j = 0; j < GPW; ++j)
            async16(gptr[j] + kt * BK, &lds[bb][(wv * GPW + j) * 512]);
    };

    // prologue: 2 tiles in flight (16 outstanding loads per wave)
    STAGE(0, 0);
    STAGE(1, 1);

    for (int kt = 0; kt < nk; ++kt) {
        // wait for THIS tile's 8 loads (kt+1's 8 remain in flight); tail drains fully
        if (kt < nk - 1) asm volatile("s_waitcnt vmcnt(8)" ::: "memory");
        else             asm volatile("s_waitcnt vmcnt(0)" ::: "memory");
        __builtin_amdgcn_s_barrier();          // every wave's kt-loads landed -> tile visible
        __builtin_amdgcn_sched_barrier(0);     // fence: no ds_read hoisted above barrier

        const u16* al = &lds[kt & 1][0];
        const u16* bl = al + BM * BK;
#pragma unroll
        for (int ks = 0; ks < 2; ++ks) {       // two 32-wide k-slices per BK=64
            const int cp = ((ks * 4 + quad) ^ (mr & 7)) * 8;   // swizzled chunk (u16 units)
            bfrag bf[4];
#pragma unroll
            for (int nf = 0; nf < 4; ++nf)
                bf[nf] = *(const bfrag*)(bl + (wc * 64 + nf * 16 + mr) * BK + cp);
#pragma unroll
            for (int mf = 0; mf < 4; ++mf) {
                bfrag af = *(const bfrag*)(al + (wr * 64 + mf * 16 + mr) * BK + cp);
#pragma unroll
                for (int nf = 0; nf < 4; ++nf)
                    acc[mf][nf] = __builtin_amdgcn_mfma_f32_16x16x32_bf16(af, bf[nf], acc[mf][nf], 0, 0, 0);
            }
        }

        __builtin_amdgcn_sched_barrier(0);     // fence: all reads stay above barrier
        __builtin_amdgcn_s_barrier();          // all waves done reading buf[kt&1]
        __builtin_amdgcn_sched_barrier(0);     // fence: stage not hoisted above barrier
        if (kt + 2 < nk) STAGE(kt + 2, kt & 1);
    }

    // epilogue. C/D layout: n = lane&15 (=mr), m = quad*4 + reg  [m89-verified]
    const float* bias_e = bias + e * NDIM;
    if constexpr (PHASE == 1) {
#pragma unroll
        for (int mf = 0; mf < 4; ++mf) {
            int mbase = wr * 64 + mf * 16 + quad * 4;
#pragma unroll
            for (int nf = 0; nf < 4; ++nf) {
                int n = n0 + wc * 64 + nf * 16 + mr;
                float bv = bias_e[n];
#pragma unroll
                for (int r = 0; r < 4; ++r) {
                    int m = m0 + mbase + r;
                    if (m < cnt) {
                        float v = acc[mf][nf][r] + bv;
                        v = v > 0.f ? v : 0.f;
                        hb[(size_t)(sbase + m) * DH + n] = f2bf(v);
                    }
                }
            }
        }
    } else {
#pragma unroll
        for (int mf = 0; mf < 4; ++mf) {
            int mbase = wr * 64 + mf * 16 + quad * 4;
#pragma unroll
            for (int r = 0; r < 4; ++r) {
                int m = m0 + mbase + r;
                if (m < cnt) {
                    int slot = sbase + m;
                    int tok = slot_token[slot];
                    float wgt = slot_wgt[slot];
                    float* orow = out + (size_t)tok * DOUT + n0 + wc * 64;
#pragma unroll
                    for (int nf = 0; nf < 4; ++nf) {
                        int nl = nf * 16 + mr;
                        float v = acc[mf][nf][r];
                        if (sp == 0) v += bias_e[n0 + wc * 64 + nl];   // bias once per token
                        atomicAdd(orow + nl, wgt * v);
                    }
                }
            }
        }
    }
}

// ---------- launch ----------
extern "C" void kernel_launch(void* const* d_in, const int* in_sizes, int n_in,
                              void* d_out, int out_size, void* d_ws, size_t ws_size,
                              hipStream_t stream) {
    const float* x  = (const float*)d_in[0];   // [4096][1024]
    const float* gw = (const float*)d_in[1];   // [16][1024]
    const float* w1 = (const float*)d_in[2];   // [16][2048][1024]
    const float* b1 = (const float*)d_in[3];   // [16][2048]
    const float* w2 = (const float*)d_in[4];   // [16][1024][2048]
    const float* b2 = (const float*)d_in[5];   // [16][1024]
    float* out = (float*)d_out;                // [4096][1024] fp32

    // workspace layout (~104.1 MiB)
    char* ws = (char*)d_ws;
    u16* xb = (u16*)ws;                                   //  8,388,608 B
    u16* wb = (u16*)(ws + 8388608);                       // 67,108,864 B (w1 then reused for w2)
    u16* hb = (u16*)(ws + 8388608 + 67108864);            // 33,554,432 B
    char* rb = ws + 109051904;
    int*   counts     = (int*)(rb);
    int*   offsets    = (int*)(rb + 64);
    int*   token_e    = (int*)(rb + 192);
    float* token_w    = (float*)(rb + 192 + 32768);
    int*   slot_token = (int*)(rb + 192 + 65536);
    float* slot_wgt   = (float*)(rb + 192 + 98304);

    zero_init<<<4096, 256, 0, stream>>>(out, (B_TOK * DOUT) / 4);
    convert_bf16<<<16384, 256, 0, stream>>>(w1, wb, (NE * DH * DI) / 8);
    gate_topk<<<1024, 256, 0, stream>>>(x, gw, token_e, token_w, xb);  // fused x->bf16
    route<<<1, 1024, 0, stream>>>(token_e, token_w, counts, offsets, slot_token, slot_wgt);
    moe_gemm<1><<<NE * 1 * (DH / 128) * (B_TOK / 128), 256, 0, stream>>>(
        xb, wb, b1, counts, offsets, slot_token, slot_wgt, hb, out);
    convert_bf16<<<16384, 256, 0, stream>>>(w2, wb, (NE * DOUT * DH) / 8);
    moe_gemm<2><<<NE * 2 * (DOUT / 128) * (B_TOK / 128), 256, 0, stream>>>(
        hb, wb, b2, counts, offsets, slot_token, slot_wgt, hb, out);
}